// Round 8
// baseline (146.630 us; speedup 1.0000x reference)
//
#include <hip/hip_runtime.h>
#include <math.h>

#define PP 16
#define VV 32
#define DD 686

__device__ __forceinline__ float clampf(float x, float lo, float hi) {
    return fminf(fmaxf(x, lo), hi);
}
__device__ __forceinline__ float fexp2(float x) { return __builtin_amdgcn_exp2f(x); }
__device__ __forceinline__ float flog2(float x) { return __builtin_amdgcn_logf(x); }   // log base-2
__device__ __forceinline__ float frsq (float x) { return __builtin_amdgcn_rsqf(x); }
__device__ __forceinline__ float zpow(float z, float pe) {
    return fexp2(pe * flog2(fmaxf(z, 1e-30f)));
}

// un-normalized support via float4 LDS chunks: h = (sum z^pe)^(1/pe), 1-homogeneous.
// sv4 = (const float4*)sv, sv 16B-aligned, 96 floats. chunk c holds verts 4c..4c+3:
// a={x0,y0,z0,x1} b={y1,z1,x2,y2} d={z2,x3,y3,z3}
__device__ __forceinline__ float spt_h4(const float4* __restrict__ sv4, float pe, float ipe,
                                        float lx, float ly, float lz)
{
    float s0 = 0.f, s1 = 0.f, s2 = 0.f, s3 = 0.f;
#pragma unroll
    for (int c = 0; c < 8; ++c) {
        float4 a = sv4[3*c+0], b = sv4[3*c+1], d = sv4[3*c+2];
        s0 += zpow(a.x*lx + a.y*ly + a.z*lz, pe);
        s1 += zpow(a.w*lx + b.x*ly + b.y*lz, pe);
        s2 += zpow(b.z*lx + b.w*ly + d.x*lz, pe);
        s3 += zpow(d.y*lx + d.z*ly + d.w*lz, pe);
    }
    return fexp2(flog2((s0+s1) + (s2+s3)) * ipe);
}

// ---- directions (match numpy f64 linspace + trig, cast f32) ----
__global__ void k_dirs(float* __restrict__ dirs)
{
    int idx = blockIdx.x * blockDim.x + threadIdx.x;
    if (idx >= DD) return;
    int i, j;
    if (idx < 684)      { i = idx / 38 + 1; j = idx - (idx / 38) * 38; }
    else if (idx == 684){ i = 0;  j = 0; }
    else                { i = 19; j = 0; }
    const double pi = 3.14159265358979323846;
    double th1 = -pi * 0.5 + (double)i * (pi / 19.0);
    double th2 = -pi       + (double)j * (pi / 19.0);
    dirs[3*idx+0] = (float)(cos(th1) * cos(th2));
    dirs[3*idx+1] = (float)(cos(th1) * sin(th2));
    dirs[3*idx+2] = (float)(sin(th1));
}

// ---- per-shape prep ----
__global__ void k_prep(const float* __restrict__ verts, const float* __restrict__ smooth,
                       double* __restrict__ dmean, float* __restrict__ fmean,
                       float* __restrict__ flocal, float* __restrict__ fpe,
                       float* __restrict__ finvpe, int BP)
{
    int bp = blockIdx.x * blockDim.x + threadIdx.x;
    if (bp >= BP) return;
    const float* vv = verts + (size_t)bp * VV * 3;
    double sx = 0.0, sy = 0.0, sz = 0.0;
#pragma unroll
    for (int k = 0; k < VV; ++k) {
        sx += (double)vv[3*k+0];
        sy += (double)vv[3*k+1];
        sz += (double)vv[3*k+2];
    }
    double mx = sx / 32.0, my = sy / 32.0, mz = sz / 32.0;
    dmean[3*bp+0] = mx; dmean[3*bp+1] = my; dmean[3*bp+2] = mz;
    fmean[3*bp+0] = (float)mx; fmean[3*bp+1] = (float)my; fmean[3*bp+2] = (float)mz;
    float* lv = flocal + (size_t)bp * VV * 3;
#pragma unroll
    for (int k = 0; k < VV; ++k) {
        lv[3*k+0] = (float)((double)vv[3*k+0] - mx);
        lv[3*k+1] = (float)((double)vv[3*k+1] - my);
        lv[3*k+2] = (float)((double)vv[3*k+2] - mz);
    }
    float pe = smooth[bp];
    fpe[bp] = pe;
    finvpe[bp] = 1.0f / pe;
}

// ---- fused shape kernel: pass1 support over dirs (+x out, +scale),
//      pass2 surf points reusing log2(h) in registers; d == x (normalize(x*s)==x)
__global__ void __launch_bounds__(256) k_shape(
        const float* __restrict__ dirs, const float* __restrict__ flocal,
        const float* __restrict__ fmean,
        const float* __restrict__ fpe, const float* __restrict__ finvpe,
        double* __restrict__ dscale,
        float* __restrict__ out2, float* __restrict__ fsurf, float* __restrict__ out4)
{
    int bp = blockIdx.x;
    __shared__ __align__(16) float sv[VV*3];
    __shared__ float red[4];
    int tid = threadIdx.x;
    if (tid < VV*3) sv[tid] = flocal[(size_t)bp*VV*3 + tid];
    __syncthreads();
    const float4* sv4 = (const float4*)sv;
    float pe = fpe[bp], ipe = finvpe[bp];
    float m0 = fmean[3*bp+0], m1 = fmean[3*bp+1], m2 = fmean[3*bp+2];

    float l2h_reg[3];
    float m = -1e38f;
#pragma unroll
    for (int it = 0; it < 3; ++it) {
        int dd = tid + 256*it;
        if (dd >= DD) break;
        float dx = dirs[3*dd+0], dy = dirs[3*dd+1], dz = dirs[3*dd+2];
        float s0=0.f,s1=0.f,s2=0.f,s3=0.f;
#pragma unroll
        for (int c = 0; c < 8; ++c) {
            float4 a = sv4[3*c+0], b = sv4[3*c+1], d = sv4[3*c+2];
            s0 += zpow(a.x*dx + a.y*dy + a.z*dz, pe);
            s1 += zpow(a.w*dx + b.x*dy + b.y*dz, pe);
            s2 += zpow(b.z*dx + b.w*dy + d.x*dz, pe);
            s3 += zpow(d.y*dx + d.z*dy + d.w*dz, pe);
        }
        float l2h = flog2((s0+s1)+(s2+s3)) * ipe;
        l2h_reg[it] = l2h;
        m = fmaxf(m, fexp2(l2h));
        float* xp = out2 + ((size_t)bp * DD + dd) * 3;
        xp[0] = dx; xp[1] = dy; xp[2] = dz;
    }
#pragma unroll
    for (int o = 32; o > 0; o >>= 1) m = fmaxf(m, __shfl_down(m, o));
    if ((tid & 63) == 0) red[tid >> 6] = m;
    __syncthreads();
    if (tid == 0) {
        m = fmaxf(fmaxf(red[0], red[1]), fmaxf(red[2], red[3]));
        dscale[bp] = (double)clampf(m, 1e-10f, 10.0f);
    }

    float pem1 = pe - 1.0f;
#pragma unroll
    for (int it = 0; it < 3; ++it) {
        int dd = tid + 256*it;
        if (dd >= DD) break;
        float dx = dirs[3*dd+0], dy = dirs[3*dd+1], dz = dirs[3*dd+2];
        float nl2h = -l2h_reg[it];
        float sxx = 0.f, syy = 0.f, szz = 0.f;
#pragma unroll
        for (int c = 0; c < 8; ++c) {
            float4 a = sv4[3*c+0], b = sv4[3*c+1], d = sv4[3*c+2];
            {
                float z = a.x*dx + a.y*dy + a.z*dz;
                float dh = fexp2(pem1 * (flog2(fmaxf(z,1e-30f)) + nl2h));
                sxx += dh * a.x; syy += dh * a.y; szz += dh * a.z;
            }
            {
                float z = a.w*dx + b.x*dy + b.y*dz;
                float dh = fexp2(pem1 * (flog2(fmaxf(z,1e-30f)) + nl2h));
                sxx += dh * a.w; syy += dh * b.x; szz += dh * b.y;
            }
            {
                float z = b.z*dx + b.w*dy + d.x*dz;
                float dh = fexp2(pem1 * (flog2(fmaxf(z,1e-30f)) + nl2h));
                sxx += dh * b.z; syy += dh * b.w; szz += dh * d.x;
            }
            {
                float z = d.y*dx + d.z*dy + d.w*dz;
                float dh = fexp2(pem1 * (flog2(fmaxf(z,1e-30f)) + nl2h));
                sxx += dh * d.y; syy += dh * d.z; szz += dh * d.w;
            }
        }
        sxx += m0; syy += m1; szz += m2;
        float* spp = fsurf + ((size_t)bp * DD + dd) * 3;
        spp[0] = sxx; spp[1] = syy; spp[2] = szz;
        float* op = out4 + ((size_t)bp * DD + dd) * 3;
        op[0] = sxx; op[1] = syy; op[2] = szz;
    }
}

// ---- overlap (f64 geometry, f32 support) ----
__global__ void __launch_bounds__(256) k_overlap(
        const float* __restrict__ flocal, const double* __restrict__ dmean,
        const float* __restrict__ fpe, const float* __restrict__ finvpe,
        float* __restrict__ out0)
{
    int b = blockIdx.x;
    __shared__ __align__(16) float sv[PP*VV*3];
    __shared__ double smd[PP*3];
    __shared__ float  spe[PP];
    __shared__ float  sipe[PP];
    __shared__ float  sh[PP*PP];
    int tid = threadIdx.x;
    for (int t = tid; t < PP*VV*3; t += 256) sv[t] = flocal[(size_t)b*PP*VV*3 + t];
    if (tid < PP*3) smd[tid]  = dmean[(size_t)b*PP*3 + tid];
    if (tid < PP)  { spe[tid] = fpe[b*PP + tid]; sipe[tid] = finvpe[b*PP + tid]; }
    __syncthreads();
    int i = tid >> 4, j = tid & 15;
    double tx = smd[3*j+0] - smd[3*i+0];
    double ty = smd[3*j+1] - smd[3*i+1];
    double tz = smd[3*j+2] - smd[3*i+2];
    double dn2 = fmin(fmax(tx*tx + ty*ty + tz*tz, 1e-20), 1e20);
    double dn = sqrt(dn2);
    float dx, dy, dz;
    if (i == j) { dx = 1.0f; dy = 0.0f; dz = 0.0f; }
    else        { dx = (float)(tx/dn); dy = (float)(ty/dn); dz = (float)(tz/dn); }
    sh[tid] = spt_h4((const float4*)&sv[i*VV*3], spe[i], sipe[i], dx, dy, dz);
    __syncthreads();
    double sep = dn - (double)sh[i*16 + j] - (double)sh[j*16 + i];
    double ov = (i == j) ? 0.0 : fmax(-sep, 0.0);
    out0[(size_t)b*PP*PP + tid] = (float)ov;
}

// ---- merged distance kernel: 3 query sets, 4 queries per thread ----
// thread handles queries n, n+256, n+512, n+768 (n = y*1024 + tid)
__global__ void __launch_bounds__(256) k_dist_all(
        const float* __restrict__ pc, int NPCv, int cPC,
        const float* __restrict__ ns, int NNSv, int cNS,
        const float* __restrict__ ob, int NOUTv,
        const float* __restrict__ flocal, const float* __restrict__ fmean,
        const float* __restrict__ fpe, const float* __restrict__ finvpe,
        float* __restrict__ out1, float* __restrict__ out5, float* __restrict__ out6)
{
    int bp = blockIdx.x;
    int b  = bp >> 4;
    __shared__ __align__(16) float sv[VV*3];
    int tid = threadIdx.x;
    if (tid < VV*3) sv[tid] = flocal[(size_t)bp*VV*3 + tid];
    __syncthreads();
    const float4* sv4 = (const float4*)sv;
    float pe = fpe[bp], ipe = finvpe[bp];
    float m0 = fmean[3*bp+0], m1 = fmean[3*bp+1], m2 = fmean[3*bp+2];

    int y = blockIdx.y;
    const float* pts; int N; float* outp;
    if (y < cPC)               { pts = pc; N = NPCv;  outp = out1; }
    else if ((y -= cPC) < cNS) { pts = ns; N = NNSv;  outp = out5; }
    else                       { y -= cNS; pts = ob; N = NOUTv; outp = out6; }

    int n0 = y * 1024 + tid;
    float lx[4], ly[4], lz[4], acc[4];
#pragma unroll
    for (int q = 0; q < 4; ++q) {
        int n = n0 + 256*q;
        if (n < N) {
            const float* pp = pts + ((size_t)b * N + n) * 3;
            lx[q] = pp[0] - m0; ly[q] = pp[1] - m1; lz[q] = pp[2] - m2;
        } else { lx[q] = 1.f; ly[q] = 0.f; lz[q] = 0.f; }
        acc[q] = 0.f;
    }
#pragma unroll
    for (int c = 0; c < 8; ++c) {
        float4 a = sv4[3*c+0], bb = sv4[3*c+1], d = sv4[3*c+2];
#pragma unroll
        for (int q = 0; q < 4; ++q) {
            acc[q] += zpow(a.x*lx[q] + a.y*ly[q] + a.z*lz[q], pe)
                    + zpow(a.w*lx[q] + bb.x*ly[q] + bb.y*lz[q], pe)
                    + zpow(bb.z*lx[q] + bb.w*ly[q] + d.x*lz[q], pe)
                    + zpow(d.y*lx[q] + d.z*ly[q] + d.w*lz[q], pe);
        }
    }
#pragma unroll
    for (int q = 0; q < 4; ++q) {
        int n = n0 + 256*q;
        if (n >= N) continue;
        float n2 = clampf(lx[q]*lx[q] + ly[q]*ly[q] + lz[q]*lz[q], 1e-40f, 1e40f);
        float invr = frsq(n2);
        float nrm = n2 * invr;
        float hs = fexp2(flog2(acc[q]) * ipe) * invr;   // homogeneity
        outp[(size_t)bp * N + n] = nrm - hs;
    }
}

// ---- surf distance: sign(nf) via f64 dot only (no sqrt/div), support f32 ----
__global__ void __launch_bounds__(256) k_surfdist(
        const float* __restrict__ fsurf, const float* __restrict__ dirs,
        const float* __restrict__ flocal, const double* __restrict__ dmean,
        const float* __restrict__ fmean,
        const float* __restrict__ fpe, const float* __restrict__ finvpe,
        const double* __restrict__ dscale,
        float* __restrict__ out3)
{
    int bp = blockIdx.x;
    int b  = bp >> 4;
    int i  = bp & 15;
    __shared__ __align__(16) float sv[VV*3];
    int tid = threadIdx.x;
    if (tid < VV*3) sv[tid] = flocal[(size_t)bp*VV*3 + tid];
    __syncthreads();
    const float4* sv4 = (const float4*)sv;
    float pe = fpe[bp], ipe = finvpe[bp];
    double sc = dscale[bp];
    double mi0 = dmean[3*bp+0], mi1 = dmean[3*bp+1], mi2 = dmean[3*bp+2];
    int q = blockIdx.y * 256 + tid;
    if (q >= PP*DD) return;
    int j  = q / DD;
    int dd = q - j * DD;
    // sign(nf): nf = t.(nl)/||nl||, ||nl||>0 -> sign(t.nl). f64, faithful rounding of nl.
    double nlx = ((double)dirs[3*dd+0] * sc + mi0) - mi0;
    double nly = ((double)dirs[3*dd+1] * sc + mi1) - mi1;
    double nlz = ((double)dirs[3*dd+2] * sc + mi2) - mi2;
    const double* mj = dmean + (size_t)(b*PP + j) * 3;
    double dot = (mj[0]-mi0)*nlx + (mj[1]-mi1)*nly + (mj[2]-mi2)*nlz;
    float dist;
    if (i == j || dot < 0.0) {
        dist = 100.0f;
    } else {
        float fm0 = fmean[3*bp+0], fm1 = fmean[3*bp+1], fm2 = fmean[3*bp+2];
        const float* sp = fsurf + ((size_t)b * PP * DD + q) * 3;
        float lx = sp[0] - fm0;
        float ly = sp[1] - fm1;
        float lz = sp[2] - fm2;
        float n2 = clampf(lx*lx + ly*ly + lz*lz, 1e-40f, 1e40f);
        float invr = frsq(n2);
        float nrm = n2 * invr;
        float hs = spt_h4(sv4, pe, ipe, lx, ly, lz) * invr;
        dist = nrm - hs;
    }
    out3[(size_t)bp * PP * DD + q] = dist;
}

extern "C" void kernel_launch(void* const* d_in, const int* in_sizes, int n_in,
                              void* d_out, int out_size, void* d_ws, size_t ws_size,
                              hipStream_t stream)
{
    // ---- runtime input binding by size ----
    const float* verts  = nullptr;
    const float* smooth = nullptr;
    const float* pcb    = nullptr;
    const float* nsb    = nullptr;
    const float* ob     = nullptr;
    const float* dirsin = nullptr;
    int Bv = 8, BP = 128, NPCv = 16384, NNSv = 8192, NOUTv = 8192;

    {
        int si = 0;
        for (int i = 1; i < n_in; ++i) if (in_sizes[i] < in_sizes[si]) si = i;
        int bp = in_sizes[si];
        bool ok = (bp > 0) && (bp % PP == 0);
        int rem[8]; int nrem = 0;
        const float* vcand = nullptr; const float* dcand = nullptr;
        if (ok) {
            for (int i = 0; i < n_in && i < 8; ++i) {
                if (i == si) continue;
                if (!vcand && in_sizes[i] == bp * VV * 3) { vcand = (const float*)d_in[i]; continue; }
                if (!dcand && in_sizes[i] == DD * 3)      { dcand = (const float*)d_in[i]; continue; }
                rem[nrem++] = i;
            }
        }
        if (ok && vcand && nrem == 3) {
            int pci = rem[0];
            for (int r = 1; r < 3; ++r) if (in_sizes[rem[r]] > in_sizes[pci]) pci = rem[r];
            int oth[2]; int no = 0;
            for (int r = 0; r < 3; ++r) if (rem[r] != pci) oth[no++] = rem[r];
            int B = bp / PP;
            int npc = in_sizes[pci] / (3 * B);
            int nns = in_sizes[oth[0]] / (3 * B);
            int nou = in_sizes[oth[1]] / (3 * B);
            if (npc > 0 && nns > 0 && nou > 0) {
                smooth = (const float*)d_in[si];
                verts  = vcand;
                dirsin = dcand;
                pcb    = (const float*)d_in[pci];
                nsb    = (const float*)d_in[oth[0]];
                ob     = (const float*)d_in[oth[1]];
                Bv = B; BP = bp; NPCv = npc; NNSv = nns; NOUTv = nou;
            }
        }
        if (!verts) {   // fallback: dict order, reference shapes
            verts  = (const float*)d_in[0];
            smooth = (const float*)d_in[1];
            pcb    = (const float*)d_in[2];
            nsb    = (const float*)d_in[3];
            ob     = (const float*)d_in[4];
            Bv = 8; BP = 128; NPCv = 16384; NNSv = 8192; NOUTv = 8192;
        }
    }

    // ---- workspace carve ----
    double* dmean  = (double*)d_ws;              // 3*BP f64
    double* dscale = dmean + 3*(size_t)BP;       // BP f64
    float*  fdirs  = (float*)(dscale + BP);      // 2058
    float*  fmean  = fdirs + DD*3;               // 3*BP
    float*  fpe    = fmean + 3*(size_t)BP;       // BP
    float*  finvpe = fpe + BP;                   // BP
    float*  flocal = finvpe + BP;                // 96*BP
    float*  fsurf  = flocal + 96*(size_t)BP;     // 3*DD*BP

    // ---- output offsets (f32 elements) ----
    float* out = (float*)d_out;
    size_t o0 = 0;
    size_t o1 = o0 + (size_t)Bv*PP*PP;
    size_t o2 = o1 + (size_t)BP*NPCv;
    size_t o3 = o2 + (size_t)BP*DD*3;
    size_t o4 = o3 + (size_t)BP*PP*DD;
    size_t o5 = o4 + (size_t)BP*DD*3;
    size_t o6 = o5 + (size_t)BP*NNSv;

    const float* dirs = dirsin ? dirsin : fdirs;
    if (!dirsin) k_dirs<<<dim3(3), 256, 0, stream>>>(fdirs);
    k_prep<<<dim3((BP + 127)/128), 128, 0, stream>>>(verts, smooth, dmean, fmean, flocal,
                                                     fpe, finvpe, BP);
    k_shape<<<dim3(BP), 256, 0, stream>>>(dirs, flocal, fmean, fpe, finvpe, dscale,
                                          out + o2, fsurf, out + o4);
    k_overlap<<<dim3(Bv), 256, 0, stream>>>(flocal, dmean, fpe, finvpe, out + o0);
    int cPC = (NPCv + 1023)/1024, cNS = (NNSv + 1023)/1024, cOU = (NOUTv + 1023)/1024;
    k_dist_all<<<dim3(BP, cPC + cNS + cOU), 256, 0, stream>>>(
        pcb, NPCv, cPC, nsb, NNSv, cNS, ob, NOUTv,
        flocal, fmean, fpe, finvpe, out + o1, out + o5, out + o6);
    k_surfdist<<<dim3(BP, (PP*DD + 255)/256), 256, 0, stream>>>(fsurf, dirs, flocal, dmean, fmean,
                                                                fpe, finvpe, dscale, out + o3);
}

// Round 9
// 141.293 us; speedup vs baseline: 1.0378x; 1.0378x over previous
//
#include <hip/hip_runtime.h>
#include <math.h>

#define PP 16
#define VV 32
#define DD 686

__device__ __forceinline__ float clampf(float x, float lo, float hi) {
    return fminf(fmaxf(x, lo), hi);
}
__device__ __forceinline__ float fexp2(float x) { return __builtin_amdgcn_exp2f(x); }
__device__ __forceinline__ float flog2(float x) { return __builtin_amdgcn_logf(x); }   // log base-2
__device__ __forceinline__ float frsq (float x) { return __builtin_amdgcn_rsqf(x); }
__device__ __forceinline__ float zpow(float z, float pe) {
    return fexp2(pe * flog2(fmaxf(z, 1e-30f)));
}

// un-normalized support via float4 LDS chunks: h = (sum z^pe)^(1/pe), 1-homogeneous.
// chunk c holds verts 4c..4c+3: a={x0,y0,z0,x1} b={y1,z1,x2,y2} d={z2,x3,y3,z3}
__device__ __forceinline__ float spt_h4(const float4* __restrict__ sv4, float pe, float ipe,
                                        float lx, float ly, float lz)
{
    float s0 = 0.f, s1 = 0.f, s2 = 0.f, s3 = 0.f;
#pragma unroll
    for (int c = 0; c < 8; ++c) {
        float4 a = sv4[3*c+0], b = sv4[3*c+1], d = sv4[3*c+2];
        s0 += zpow(a.x*lx + a.y*ly + a.z*lz, pe);
        s1 += zpow(a.w*lx + b.x*ly + b.y*lz, pe);
        s2 += zpow(b.z*lx + b.w*ly + d.x*lz, pe);
        s3 += zpow(d.y*lx + d.z*ly + d.w*lz, pe);
    }
    return fexp2(flog2((s0+s1) + (s2+s3)) * ipe);
}

// ================= K0: setup = dirs + prep (role by block) =================
__global__ void k_setup(const float* __restrict__ verts, const float* __restrict__ smooth,
                        double* __restrict__ dmean, float* __restrict__ fmean,
                        float* __restrict__ flocal, float* __restrict__ fpe,
                        float* __restrict__ finvpe, float* __restrict__ fdirs,
                        int BP, int doDirs)
{
    int blk = blockIdx.x;
    int tid = threadIdx.x;
    if (blk < 3) {                       // ---- dirs role ----
        if (!doDirs) return;
        int idx = blk * 256 + tid;
        if (idx >= DD) return;
        int i, j;
        if (idx < 684)      { i = idx / 38 + 1; j = idx - (idx / 38) * 38; }
        else if (idx == 684){ i = 0;  j = 0; }
        else                { i = 19; j = 0; }
        const double pi = 3.14159265358979323846;
        double th1 = -pi * 0.5 + (double)i * (pi / 19.0);
        double th2 = -pi       + (double)j * (pi / 19.0);
        fdirs[3*idx+0] = (float)(cos(th1) * cos(th2));
        fdirs[3*idx+1] = (float)(cos(th1) * sin(th2));
        fdirs[3*idx+2] = (float)(sin(th1));
        return;
    }
    // ---- prep role ----
    int bp = (blk - 3) * 256 + tid;
    if (bp >= BP) return;
    const float* vv = verts + (size_t)bp * VV * 3;
    double sx = 0.0, sy = 0.0, sz = 0.0;
#pragma unroll
    for (int k = 0; k < VV; ++k) {
        sx += (double)vv[3*k+0];
        sy += (double)vv[3*k+1];
        sz += (double)vv[3*k+2];
    }
    double mx = sx / 32.0, my = sy / 32.0, mz = sz / 32.0;
    dmean[3*bp+0] = mx; dmean[3*bp+1] = my; dmean[3*bp+2] = mz;
    fmean[3*bp+0] = (float)mx; fmean[3*bp+1] = (float)my; fmean[3*bp+2] = (float)mz;
    float* lv = flocal + (size_t)bp * VV * 3;
#pragma unroll
    for (int k = 0; k < VV; ++k) {
        lv[3*k+0] = (float)((double)vv[3*k+0] - mx);
        lv[3*k+1] = (float)((double)vv[3*k+1] - my);
        lv[3*k+2] = (float)((double)vv[3*k+2] - mz);
    }
    float pe = smooth[bp];
    fpe[bp] = pe;
    finvpe[bp] = 1.0f / pe;
}

// ============ K1: mid = shape (blocks 0..BP) + overlap (blocks BP..BP+Bv) ============
__global__ void __launch_bounds__(256) k_mid(
        const float* __restrict__ dirs, const float* __restrict__ flocal,
        const float* __restrict__ fmean, const double* __restrict__ dmean,
        const float* __restrict__ fpe, const float* __restrict__ finvpe,
        double* __restrict__ dscale,
        float* __restrict__ out2, float* __restrict__ fsurf, float* __restrict__ out4,
        float* __restrict__ out0, int BP)
{
    int tid = threadIdx.x;
    if (blockIdx.x < (unsigned)BP) {
        // ---------------- shape role ----------------
        int bp = blockIdx.x;
        __shared__ __align__(16) float sv[VV*3];
        __shared__ float red[4];
        if (tid < VV*3) sv[tid] = flocal[(size_t)bp*VV*3 + tid];
        __syncthreads();
        const float4* sv4 = (const float4*)sv;
        float pe = fpe[bp], ipe = finvpe[bp];
        float m0 = fmean[3*bp+0], m1 = fmean[3*bp+1], m2 = fmean[3*bp+2];

        float l2h_reg[3];
        float m = -1e38f;
#pragma unroll
        for (int it = 0; it < 3; ++it) {
            int dd = tid + 256*it;
            if (dd >= DD) break;
            float dx = dirs[3*dd+0], dy = dirs[3*dd+1], dz = dirs[3*dd+2];
            float s0=0.f,s1=0.f,s2=0.f,s3=0.f;
#pragma unroll
            for (int c = 0; c < 8; ++c) {
                float4 a = sv4[3*c+0], b = sv4[3*c+1], d = sv4[3*c+2];
                s0 += zpow(a.x*dx + a.y*dy + a.z*dz, pe);
                s1 += zpow(a.w*dx + b.x*dy + b.y*dz, pe);
                s2 += zpow(b.z*dx + b.w*dy + d.x*dz, pe);
                s3 += zpow(d.y*dx + d.z*dy + d.w*dz, pe);
            }
            float l2h = flog2((s0+s1)+(s2+s3)) * ipe;
            l2h_reg[it] = l2h;
            m = fmaxf(m, fexp2(l2h));
            float* xp = out2 + ((size_t)bp * DD + dd) * 3;
            xp[0] = dx; xp[1] = dy; xp[2] = dz;
        }
#pragma unroll
        for (int o = 32; o > 0; o >>= 1) m = fmaxf(m, __shfl_down(m, o));
        if ((tid & 63) == 0) red[tid >> 6] = m;
        __syncthreads();
        if (tid == 0) {
            m = fmaxf(fmaxf(red[0], red[1]), fmaxf(red[2], red[3]));
            dscale[bp] = (double)clampf(m, 1e-10f, 10.0f);
        }

        float pem1 = pe - 1.0f;
#pragma unroll
        for (int it = 0; it < 3; ++it) {
            int dd = tid + 256*it;
            if (dd >= DD) break;
            float dx = dirs[3*dd+0], dy = dirs[3*dd+1], dz = dirs[3*dd+2];
            float nl2h = -l2h_reg[it];
            float sxx = 0.f, syy = 0.f, szz = 0.f;
#pragma unroll
            for (int c = 0; c < 8; ++c) {
                float4 a = sv4[3*c+0], b = sv4[3*c+1], d = sv4[3*c+2];
                {
                    float z = a.x*dx + a.y*dy + a.z*dz;
                    float dh = fexp2(pem1 * (flog2(fmaxf(z,1e-30f)) + nl2h));
                    sxx += dh * a.x; syy += dh * a.y; szz += dh * a.z;
                }
                {
                    float z = a.w*dx + b.x*dy + b.y*dz;
                    float dh = fexp2(pem1 * (flog2(fmaxf(z,1e-30f)) + nl2h));
                    sxx += dh * a.w; syy += dh * b.x; szz += dh * b.y;
                }
                {
                    float z = b.z*dx + b.w*dy + d.x*dz;
                    float dh = fexp2(pem1 * (flog2(fmaxf(z,1e-30f)) + nl2h));
                    sxx += dh * b.z; syy += dh * b.w; szz += dh * d.x;
                }
                {
                    float z = d.y*dx + d.z*dy + d.w*dz;
                    float dh = fexp2(pem1 * (flog2(fmaxf(z,1e-30f)) + nl2h));
                    sxx += dh * d.y; syy += dh * d.z; szz += dh * d.w;
                }
            }
            sxx += m0; syy += m1; szz += m2;
            float* spp = fsurf + ((size_t)bp * DD + dd) * 3;
            spp[0] = sxx; spp[1] = syy; spp[2] = szz;
            float* op = out4 + ((size_t)bp * DD + dd) * 3;
            op[0] = sxx; op[1] = syy; op[2] = szz;
        }
        return;
    }
    // ---------------- overlap role ----------------
    int b = blockIdx.x - BP;
    __shared__ __align__(16) float osv[PP*VV*3];
    __shared__ double smd[PP*3];
    __shared__ float  spe[PP];
    __shared__ float  sipe[PP];
    __shared__ float  sh[PP*PP];
    for (int t = tid; t < PP*VV*3; t += 256) osv[t] = flocal[(size_t)b*PP*VV*3 + t];
    if (tid < PP*3) smd[tid]  = dmean[(size_t)b*PP*3 + tid];
    if (tid < PP)  { spe[tid] = fpe[b*PP + tid]; sipe[tid] = finvpe[b*PP + tid]; }
    __syncthreads();
    int i = tid >> 4, j = tid & 15;
    double tx = smd[3*j+0] - smd[3*i+0];
    double ty = smd[3*j+1] - smd[3*i+1];
    double tz = smd[3*j+2] - smd[3*i+2];
    double dn2 = fmin(fmax(tx*tx + ty*ty + tz*tz, 1e-20), 1e20);
    double dn = sqrt(dn2);
    float dx, dy, dz;
    if (i == j) { dx = 1.0f; dy = 0.0f; dz = 0.0f; }
    else        { dx = (float)(tx/dn); dy = (float)(ty/dn); dz = (float)(tz/dn); }
    sh[tid] = spt_h4((const float4*)&osv[i*VV*3], spe[i], sipe[i], dx, dy, dz);
    __syncthreads();
    double sep = dn - (double)sh[i*16 + j] - (double)sh[j*16 + i];
    double ov = (i == j) ? 0.0 : fmax(-sep, 0.0);
    out0[(size_t)b*PP*PP + tid] = (float)ov;
}

// ============ K2: heavy = dist_all (y < cPC+cNS+cOU) + surfdist (rest) ============
__global__ void __launch_bounds__(256) k_heavy(
        const float* __restrict__ pc, int NPCv, int cPC,
        const float* __restrict__ ns, int NNSv, int cNS,
        const float* __restrict__ ob, int NOUTv, int cOU,
        const float* __restrict__ fsurf, const float* __restrict__ dirs,
        const float* __restrict__ flocal, const double* __restrict__ dmean,
        const float* __restrict__ fmean,
        const float* __restrict__ fpe, const float* __restrict__ finvpe,
        const double* __restrict__ dscale,
        float* __restrict__ out1, float* __restrict__ out5, float* __restrict__ out6,
        float* __restrict__ out3)
{
    int bp = blockIdx.x;
    int b  = bp >> 4;
    int tid = threadIdx.x;
    __shared__ __align__(16) float sv[VV*3];
    if (tid < VV*3) sv[tid] = flocal[(size_t)bp*VV*3 + tid];
    __syncthreads();
    const float4* sv4 = (const float4*)sv;
    float pe = fpe[bp], ipe = finvpe[bp];
    int y = blockIdx.y;
    int cD = cPC + cNS + cOU;

    if (y < cD) {
        // ---------------- dist role (4 queries/thread) ----------------
        float m0 = fmean[3*bp+0], m1 = fmean[3*bp+1], m2 = fmean[3*bp+2];
        const float* pts; int N; float* outp;
        if (y < cPC)               { pts = pc; N = NPCv;  outp = out1; }
        else if ((y -= cPC) < cNS) { pts = ns; N = NNSv;  outp = out5; }
        else                       { y -= cNS; pts = ob; N = NOUTv; outp = out6; }

        int n0 = y * 1024 + tid;
        float lx[4], ly[4], lz[4], acc[4];
#pragma unroll
        for (int q = 0; q < 4; ++q) {
            int n = n0 + 256*q;
            if (n < N) {
                const float* pp = pts + ((size_t)b * N + n) * 3;
                lx[q] = pp[0] - m0; ly[q] = pp[1] - m1; lz[q] = pp[2] - m2;
            } else { lx[q] = 1.f; ly[q] = 0.f; lz[q] = 0.f; }
            acc[q] = 0.f;
        }
#pragma unroll
        for (int c = 0; c < 8; ++c) {
            float4 a = sv4[3*c+0], bb = sv4[3*c+1], d = sv4[3*c+2];
#pragma unroll
            for (int q = 0; q < 4; ++q) {
                acc[q] += zpow(a.x*lx[q] + a.y*ly[q] + a.z*lz[q], pe)
                        + zpow(a.w*lx[q] + bb.x*ly[q] + bb.y*lz[q], pe)
                        + zpow(bb.z*lx[q] + bb.w*ly[q] + d.x*lz[q], pe)
                        + zpow(d.y*lx[q] + d.z*ly[q] + d.w*lz[q], pe);
            }
        }
#pragma unroll
        for (int q = 0; q < 4; ++q) {
            int n = n0 + 256*q;
            if (n >= N) continue;
            float n2 = clampf(lx[q]*lx[q] + ly[q]*ly[q] + lz[q]*lz[q], 1e-40f, 1e40f);
            float invr = frsq(n2);
            float nrm = n2 * invr;
            float hs = fexp2(flog2(acc[q]) * ipe) * invr;   // homogeneity
            outp[(size_t)bp * N + n] = nrm - hs;
        }
        return;
    }
    // ---------------- surfdist role ----------------
    int i = bp & 15;
    int q = (y - cD) * 256 + tid;
    if (q >= PP*DD) return;
    int j  = q / DD;
    int dd = q - j * DD;
    double sc  = dscale[bp];
    double mi0 = dmean[3*bp+0], mi1 = dmean[3*bp+1], mi2 = dmean[3*bp+2];
    // sign(nf): nf = t.(nl)/||nl||, ||nl||>0 -> sign(t.nl). f64, faithful rounding of nl.
    double nlx = ((double)dirs[3*dd+0] * sc + mi0) - mi0;
    double nly = ((double)dirs[3*dd+1] * sc + mi1) - mi1;
    double nlz = ((double)dirs[3*dd+2] * sc + mi2) - mi2;
    const double* mj = dmean + (size_t)(b*PP + j) * 3;
    double dot = (mj[0]-mi0)*nlx + (mj[1]-mi1)*nly + (mj[2]-mi2)*nlz;
    float dist;
    if (i == j || dot < 0.0) {
        dist = 100.0f;
    } else {
        float fm0 = fmean[3*bp+0], fm1 = fmean[3*bp+1], fm2 = fmean[3*bp+2];
        const float* sp = fsurf + ((size_t)b * PP * DD + q) * 3;
        float lx = sp[0] - fm0;
        float ly = sp[1] - fm1;
        float lz = sp[2] - fm2;
        float n2 = clampf(lx*lx + ly*ly + lz*lz, 1e-40f, 1e40f);
        float invr = frsq(n2);
        float nrm = n2 * invr;
        float hs = spt_h4(sv4, pe, ipe, lx, ly, lz) * invr;
        dist = nrm - hs;
    }
    out3[(size_t)bp * PP * DD + q] = dist;
}

extern "C" void kernel_launch(void* const* d_in, const int* in_sizes, int n_in,
                              void* d_out, int out_size, void* d_ws, size_t ws_size,
                              hipStream_t stream)
{
    // ---- runtime input binding by size ----
    const float* verts  = nullptr;
    const float* smooth = nullptr;
    const float* pcb    = nullptr;
    const float* nsb    = nullptr;
    const float* ob     = nullptr;
    const float* dirsin = nullptr;
    int Bv = 8, BP = 128, NPCv = 16384, NNSv = 8192, NOUTv = 8192;

    {
        int si = 0;
        for (int i = 1; i < n_in; ++i) if (in_sizes[i] < in_sizes[si]) si = i;
        int bp = in_sizes[si];
        bool ok = (bp > 0) && (bp % PP == 0);
        int rem[8]; int nrem = 0;
        const float* vcand = nullptr; const float* dcand = nullptr;
        if (ok) {
            for (int i = 0; i < n_in && i < 8; ++i) {
                if (i == si) continue;
                if (!vcand && in_sizes[i] == bp * VV * 3) { vcand = (const float*)d_in[i]; continue; }
                if (!dcand && in_sizes[i] == DD * 3)      { dcand = (const float*)d_in[i]; continue; }
                rem[nrem++] = i;
            }
        }
        if (ok && vcand && nrem == 3) {
            int pci = rem[0];
            for (int r = 1; r < 3; ++r) if (in_sizes[rem[r]] > in_sizes[pci]) pci = rem[r];
            int oth[2]; int no = 0;
            for (int r = 0; r < 3; ++r) if (rem[r] != pci) oth[no++] = rem[r];
            int B = bp / PP;
            int npc = in_sizes[pci] / (3 * B);
            int nns = in_sizes[oth[0]] / (3 * B);
            int nou = in_sizes[oth[1]] / (3 * B);
            if (npc > 0 && nns > 0 && nou > 0) {
                smooth = (const float*)d_in[si];
                verts  = vcand;
                dirsin = dcand;
                pcb    = (const float*)d_in[pci];
                nsb    = (const float*)d_in[oth[0]];
                ob     = (const float*)d_in[oth[1]];
                Bv = B; BP = bp; NPCv = npc; NNSv = nns; NOUTv = nou;
            }
        }
        if (!verts) {   // fallback: dict order, reference shapes
            verts  = (const float*)d_in[0];
            smooth = (const float*)d_in[1];
            pcb    = (const float*)d_in[2];
            nsb    = (const float*)d_in[3];
            ob     = (const float*)d_in[4];
            Bv = 8; BP = 128; NPCv = 16384; NNSv = 8192; NOUTv = 8192;
        }
    }

    // ---- workspace carve ----
    double* dmean  = (double*)d_ws;              // 3*BP f64
    double* dscale = dmean + 3*(size_t)BP;       // BP f64
    float*  fdirs  = (float*)(dscale + BP);      // 2058
    float*  fmean  = fdirs + DD*3;               // 3*BP
    float*  fpe    = fmean + 3*(size_t)BP;       // BP
    float*  finvpe = fpe + BP;                   // BP
    float*  flocal = finvpe + BP;                // 96*BP
    float*  fsurf  = flocal + 96*(size_t)BP;     // 3*DD*BP

    // ---- output offsets (f32 elements) ----
    float* out = (float*)d_out;
    size_t o0 = 0;
    size_t o1 = o0 + (size_t)Bv*PP*PP;
    size_t o2 = o1 + (size_t)BP*NPCv;
    size_t o3 = o2 + (size_t)BP*DD*3;
    size_t o4 = o3 + (size_t)BP*PP*DD;
    size_t o5 = o4 + (size_t)BP*DD*3;
    size_t o6 = o5 + (size_t)BP*NNSv;

    const float* dirs = dirsin ? dirsin : fdirs;
    int nPrep = (BP + 255) / 256;
    k_setup<<<dim3(3 + nPrep), 256, 0, stream>>>(verts, smooth, dmean, fmean, flocal,
                                                 fpe, finvpe, fdirs, BP, dirsin ? 0 : 1);
    k_mid<<<dim3(BP + Bv), 256, 0, stream>>>(dirs, flocal, fmean, dmean, fpe, finvpe,
                                             dscale, out + o2, fsurf, out + o4, out + o0, BP);
    int cPC = (NPCv + 1023)/1024, cNS = (NNSv + 1023)/1024, cOU = (NOUTv + 1023)/1024;
    int cSD = (PP*DD + 255)/256;
    k_heavy<<<dim3(BP, cPC + cNS + cOU + cSD), 256, 0, stream>>>(
        pcb, NPCv, cPC, nsb, NNSv, cNS, ob, NOUTv, cOU,
        fsurf, dirs, flocal, dmean, fmean, fpe, finvpe, dscale,
        out + o1, out + o5, out + o6, out + o3);
}

// Round 10
// 134.359 us; speedup vs baseline: 1.0913x; 1.0516x over previous
//
#include <hip/hip_runtime.h>
#include <math.h>

#define PP 16
#define VV 32
#define DD 686

__device__ __forceinline__ float clampf(float x, float lo, float hi) {
    return fminf(fmaxf(x, lo), hi);
}
__device__ __forceinline__ float fexp2(float x) { return __builtin_amdgcn_exp2f(x); }
__device__ __forceinline__ float flog2(float x) { return __builtin_amdgcn_logf(x); }   // log base-2
__device__ __forceinline__ float frsq (float x) { return __builtin_amdgcn_rsqf(x); }
__device__ __forceinline__ float zpow(float z, float pe) {
    return fexp2(pe * flog2(fmaxf(z, 1e-30f)));
}

// un-normalized support via float4 LDS chunks: h = (sum z^pe)^(1/pe), 1-homogeneous.
// chunk c holds verts 4c..4c+3: a={x0,y0,z0,x1} b={y1,z1,x2,y2} d={z2,x3,y3,z3}
__device__ __forceinline__ float spt_h4(const float4* __restrict__ sv4, float pe, float ipe,
                                        float lx, float ly, float lz)
{
    float s0 = 0.f, s1 = 0.f, s2 = 0.f, s3 = 0.f;
#pragma unroll
    for (int c = 0; c < 8; ++c) {
        float4 a = sv4[3*c+0], b = sv4[3*c+1], d = sv4[3*c+2];
        s0 += zpow(a.x*lx + a.y*ly + a.z*lz, pe);
        s1 += zpow(a.w*lx + b.x*ly + b.y*lz, pe);
        s2 += zpow(b.z*lx + b.w*ly + d.x*lz, pe);
        s3 += zpow(d.y*lx + d.z*ly + d.w*lz, pe);
    }
    return fexp2(flog2((s0+s1) + (s2+s3)) * ipe);
}

// ================= K0: setup = dirs (f64 trig — sign-critical downstream) + prep ========
__global__ void k_setup(const float* __restrict__ verts, const float* __restrict__ smooth,
                        double* __restrict__ dmean, float* __restrict__ fmean,
                        float* __restrict__ flocal, float* __restrict__ fpe,
                        float* __restrict__ finvpe, float* __restrict__ fdirs,
                        int BP, int doDirs)
{
    int blk = blockIdx.x;
    int tid = threadIdx.x;
    if (blk < 3) {                       // ---- dirs role ----
        if (!doDirs) return;
        int idx = blk * 256 + tid;
        if (idx >= DD) return;
        int i, j;
        if (idx < 684)      { i = idx / 38 + 1; j = idx - (idx / 38) * 38; }
        else if (idx == 684){ i = 0;  j = 0; }
        else                { i = 19; j = 0; }
        const double pi = 3.14159265358979323846;
        double th1 = -pi * 0.5 + (double)i * (pi / 19.0);
        double th2 = -pi       + (double)j * (pi / 19.0);
        fdirs[3*idx+0] = (float)(cos(th1) * cos(th2));
        fdirs[3*idx+1] = (float)(cos(th1) * sin(th2));
        fdirs[3*idx+2] = (float)(sin(th1));
        return;
    }
    // ---- prep role ----
    int bp = (blk - 3) * 256 + tid;
    if (bp >= BP) return;
    const float* vv = verts + (size_t)bp * VV * 3;
    double sx = 0.0, sy = 0.0, sz = 0.0;
#pragma unroll
    for (int k = 0; k < VV; ++k) {
        sx += (double)vv[3*k+0];
        sy += (double)vv[3*k+1];
        sz += (double)vv[3*k+2];
    }
    double mx = sx / 32.0, my = sy / 32.0, mz = sz / 32.0;
    dmean[3*bp+0] = mx; dmean[3*bp+1] = my; dmean[3*bp+2] = mz;
    fmean[3*bp+0] = (float)mx; fmean[3*bp+1] = (float)my; fmean[3*bp+2] = (float)mz;
    float* lv = flocal + (size_t)bp * VV * 3;
#pragma unroll
    for (int k = 0; k < VV; ++k) {
        lv[3*k+0] = (float)((double)vv[3*k+0] - mx);
        lv[3*k+1] = (float)((double)vv[3*k+1] - my);
        lv[3*k+2] = (float)((double)vv[3*k+2] - mz);
    }
    float pe = smooth[bp];
    fpe[bp] = pe;
    finvpe[bp] = 1.0f / pe;
}

// ======= K1: work = shape [0,BP) + overlap [BP,BP+Bv) + dist [BP+Bv, +BP*cD) =======
// shape/overlap (small, serial before) now hide inside dist's occupancy shadow.
__global__ void __launch_bounds__(256) k_work(
        const float* __restrict__ dirs, const float* __restrict__ flocal,
        const float* __restrict__ fmean, const double* __restrict__ dmean,
        const float* __restrict__ fpe, const float* __restrict__ finvpe,
        double* __restrict__ dscale,
        const float* __restrict__ pc, int NPCv, int cPC,
        const float* __restrict__ ns, int NNSv, int cNS,
        const float* __restrict__ ob, int NOUTv, int cD,
        float* __restrict__ out2, float* __restrict__ fsurf, float* __restrict__ out4,
        float* __restrict__ out0,
        float* __restrict__ out1, float* __restrict__ out5, float* __restrict__ out6,
        int BP, int Bv)
{
    int tid = threadIdx.x;
    int blk = blockIdx.x;

    if (blk < BP) {
        // ---------------- shape role ----------------
        int bp = blk;
        __shared__ __align__(16) float sv[VV*3];
        __shared__ float red[4];
        if (tid < VV*3) sv[tid] = flocal[(size_t)bp*VV*3 + tid];
        __syncthreads();
        const float4* sv4 = (const float4*)sv;
        float pe = fpe[bp], ipe = finvpe[bp];
        float m0 = fmean[3*bp+0], m1 = fmean[3*bp+1], m2 = fmean[3*bp+2];

        float l2h_reg[3];
        float m = -1e38f;
#pragma unroll
        for (int it = 0; it < 3; ++it) {
            int dd = tid + 256*it;
            if (dd >= DD) break;
            float dx = dirs[3*dd+0], dy = dirs[3*dd+1], dz = dirs[3*dd+2];
            float s0=0.f,s1=0.f,s2=0.f,s3=0.f;
#pragma unroll
            for (int c = 0; c < 8; ++c) {
                float4 a = sv4[3*c+0], b = sv4[3*c+1], d = sv4[3*c+2];
                s0 += zpow(a.x*dx + a.y*dy + a.z*dz, pe);
                s1 += zpow(a.w*dx + b.x*dy + b.y*dz, pe);
                s2 += zpow(b.z*dx + b.w*dy + d.x*dz, pe);
                s3 += zpow(d.y*dx + d.z*dy + d.w*dz, pe);
            }
            float l2h = flog2((s0+s1)+(s2+s3)) * ipe;
            l2h_reg[it] = l2h;
            m = fmaxf(m, fexp2(l2h));
            float* xp = out2 + ((size_t)bp * DD + dd) * 3;
            xp[0] = dx; xp[1] = dy; xp[2] = dz;
        }
#pragma unroll
        for (int o = 32; o > 0; o >>= 1) m = fmaxf(m, __shfl_down(m, o));
        if ((tid & 63) == 0) red[tid >> 6] = m;
        __syncthreads();
        if (tid == 0) {
            m = fmaxf(fmaxf(red[0], red[1]), fmaxf(red[2], red[3]));
            dscale[bp] = (double)clampf(m, 1e-10f, 10.0f);
        }

        float pem1 = pe - 1.0f;
#pragma unroll
        for (int it = 0; it < 3; ++it) {
            int dd = tid + 256*it;
            if (dd >= DD) break;
            float dx = dirs[3*dd+0], dy = dirs[3*dd+1], dz = dirs[3*dd+2];
            float nl2h = -l2h_reg[it];
            float sxx = 0.f, syy = 0.f, szz = 0.f;
#pragma unroll
            for (int c = 0; c < 8; ++c) {
                float4 a = sv4[3*c+0], b = sv4[3*c+1], d = sv4[3*c+2];
                {
                    float z = a.x*dx + a.y*dy + a.z*dz;
                    float dh = fexp2(pem1 * (flog2(fmaxf(z,1e-30f)) + nl2h));
                    sxx += dh * a.x; syy += dh * a.y; szz += dh * a.z;
                }
                {
                    float z = a.w*dx + b.x*dy + b.y*dz;
                    float dh = fexp2(pem1 * (flog2(fmaxf(z,1e-30f)) + nl2h));
                    sxx += dh * a.w; syy += dh * b.x; szz += dh * b.y;
                }
                {
                    float z = b.z*dx + b.w*dy + d.x*dz;
                    float dh = fexp2(pem1 * (flog2(fmaxf(z,1e-30f)) + nl2h));
                    sxx += dh * b.z; syy += dh * b.w; szz += dh * d.x;
                }
                {
                    float z = d.y*dx + d.z*dy + d.w*dz;
                    float dh = fexp2(pem1 * (flog2(fmaxf(z,1e-30f)) + nl2h));
                    sxx += dh * d.y; syy += dh * d.z; szz += dh * d.w;
                }
            }
            sxx += m0; syy += m1; szz += m2;
            float* spp = fsurf + ((size_t)bp * DD + dd) * 3;
            spp[0] = sxx; spp[1] = syy; spp[2] = szz;
            float* op = out4 + ((size_t)bp * DD + dd) * 3;
            op[0] = sxx; op[1] = syy; op[2] = szz;
        }
        return;
    }
    if (blk < BP + Bv) {
        // ---------------- overlap role ----------------
        int b = blk - BP;
        __shared__ __align__(16) float osv[PP*VV*3];
        __shared__ double smd[PP*3];
        __shared__ float  spe[PP];
        __shared__ float  sipe[PP];
        __shared__ float  sh[PP*PP];
        for (int t = tid; t < PP*VV*3; t += 256) osv[t] = flocal[(size_t)b*PP*VV*3 + t];
        if (tid < PP*3) smd[tid]  = dmean[(size_t)b*PP*3 + tid];
        if (tid < PP)  { spe[tid] = fpe[b*PP + tid]; sipe[tid] = finvpe[b*PP + tid]; }
        __syncthreads();
        int i = tid >> 4, j = tid & 15;
        double tx = smd[3*j+0] - smd[3*i+0];
        double ty = smd[3*j+1] - smd[3*i+1];
        double tz = smd[3*j+2] - smd[3*i+2];
        double dn2 = fmin(fmax(tx*tx + ty*ty + tz*tz, 1e-20), 1e20);
        double dn = sqrt(dn2);
        float dx, dy, dz;
        if (i == j) { dx = 1.0f; dy = 0.0f; dz = 0.0f; }
        else        { dx = (float)(tx/dn); dy = (float)(ty/dn); dz = (float)(tz/dn); }
        sh[tid] = spt_h4((const float4*)&osv[i*VV*3], spe[i], sipe[i], dx, dy, dz);
        __syncthreads();
        double sep = dn - (double)sh[i*16 + j] - (double)sh[j*16 + i];
        double ov = (i == j) ? 0.0 : fmax(-sep, 0.0);
        out0[(size_t)b*PP*PP + tid] = (float)ov;
        return;
    }
    // ---------------- dist role (4 queries/thread) ----------------
    int lin = blk - BP - Bv;
    int bp  = lin / cD;
    int y   = lin - bp * cD;
    int b   = bp >> 4;
    __shared__ __align__(16) float sv[VV*3];
    if (tid < VV*3) sv[tid] = flocal[(size_t)bp*VV*3 + tid];
    __syncthreads();
    const float4* sv4 = (const float4*)sv;
    float pe = fpe[bp], ipe = finvpe[bp];
    float m0 = fmean[3*bp+0], m1 = fmean[3*bp+1], m2 = fmean[3*bp+2];
    const float* pts; int N; float* outp;
    if (y < cPC)               { pts = pc; N = NPCv;  outp = out1; }
    else if ((y -= cPC) < cNS) { pts = ns; N = NNSv;  outp = out5; }
    else                       { y -= cNS; pts = ob; N = NOUTv; outp = out6; }

    int n0 = y * 1024 + tid;
    float lx[4], ly[4], lz[4], acc[4];
#pragma unroll
    for (int q = 0; q < 4; ++q) {
        int n = n0 + 256*q;
        if (n < N) {
            const float* pp = pts + ((size_t)b * N + n) * 3;
            lx[q] = pp[0] - m0; ly[q] = pp[1] - m1; lz[q] = pp[2] - m2;
        } else { lx[q] = 1.f; ly[q] = 0.f; lz[q] = 0.f; }
        acc[q] = 0.f;
    }
#pragma unroll
    for (int c = 0; c < 8; ++c) {
        float4 a = sv4[3*c+0], bb = sv4[3*c+1], d = sv4[3*c+2];
#pragma unroll
        for (int q = 0; q < 4; ++q) {
            acc[q] += zpow(a.x*lx[q] + a.y*ly[q] + a.z*lz[q], pe)
                    + zpow(a.w*lx[q] + bb.x*ly[q] + bb.y*lz[q], pe)
                    + zpow(bb.z*lx[q] + bb.w*ly[q] + d.x*lz[q], pe)
                    + zpow(d.y*lx[q] + d.z*ly[q] + d.w*lz[q], pe);
        }
    }
#pragma unroll
    for (int q = 0; q < 4; ++q) {
        int n = n0 + 256*q;
        if (n >= N) continue;
        float n2 = clampf(lx[q]*lx[q] + ly[q]*ly[q] + lz[q]*lz[q], 1e-40f, 1e40f);
        float invr = frsq(n2);
        float nrm = n2 * invr;
        float hs = fexp2(flog2(acc[q]) * ipe) * invr;   // homogeneity
        outp[(size_t)bp * N + n] = nrm - hs;
    }
}

// ============ K2: surfdist (needs fsurf/dscale from K1; launch boundary = sync) ============
__global__ void __launch_bounds__(256) k_surfdist(
        const float* __restrict__ fsurf, const float* __restrict__ dirs,
        const float* __restrict__ flocal, const double* __restrict__ dmean,
        const float* __restrict__ fmean,
        const float* __restrict__ fpe, const float* __restrict__ finvpe,
        const double* __restrict__ dscale,
        float* __restrict__ out3)
{
    int bp = blockIdx.x;
    int b  = bp >> 4;
    int i  = bp & 15;
    int tid = threadIdx.x;
    __shared__ __align__(16) float sv[VV*3];
    if (tid < VV*3) sv[tid] = flocal[(size_t)bp*VV*3 + tid];
    __syncthreads();
    const float4* sv4 = (const float4*)sv;
    float pe = fpe[bp], ipe = finvpe[bp];
    int q = blockIdx.y * 256 + tid;
    if (q >= PP*DD) return;
    int j  = q / DD;
    int dd = q - j * DD;
    double sc  = dscale[bp];
    double mi0 = dmean[3*bp+0], mi1 = dmean[3*bp+1], mi2 = dmean[3*bp+2];
    // sign(nf): nf = t.(nl)/||nl||, ||nl||>0 -> sign(t.nl). f64, faithful rounding of nl.
    double nlx = ((double)dirs[3*dd+0] * sc + mi0) - mi0;
    double nly = ((double)dirs[3*dd+1] * sc + mi1) - mi1;
    double nlz = ((double)dirs[3*dd+2] * sc + mi2) - mi2;
    const double* mj = dmean + (size_t)(b*PP + j) * 3;
    double dot = (mj[0]-mi0)*nlx + (mj[1]-mi1)*nly + (mj[2]-mi2)*nlz;
    float dist;
    if (i == j || dot < 0.0) {
        dist = 100.0f;
    } else {
        float fm0 = fmean[3*bp+0], fm1 = fmean[3*bp+1], fm2 = fmean[3*bp+2];
        const float* sp = fsurf + ((size_t)b * PP * DD + q) * 3;
        float lx = sp[0] - fm0;
        float ly = sp[1] - fm1;
        float lz = sp[2] - fm2;
        float n2 = clampf(lx*lx + ly*ly + lz*lz, 1e-40f, 1e40f);
        float invr = frsq(n2);
        float nrm = n2 * invr;
        float hs = spt_h4(sv4, pe, ipe, lx, ly, lz) * invr;
        dist = nrm - hs;
    }
    out3[(size_t)bp * PP * DD + q] = dist;
}

extern "C" void kernel_launch(void* const* d_in, const int* in_sizes, int n_in,
                              void* d_out, int out_size, void* d_ws, size_t ws_size,
                              hipStream_t stream)
{
    // ---- runtime input binding by size ----
    const float* verts  = nullptr;
    const float* smooth = nullptr;
    const float* pcb    = nullptr;
    const float* nsb    = nullptr;
    const float* ob     = nullptr;
    const float* dirsin = nullptr;
    int Bv = 8, BP = 128, NPCv = 16384, NNSv = 8192, NOUTv = 8192;

    {
        int si = 0;
        for (int i = 1; i < n_in; ++i) if (in_sizes[i] < in_sizes[si]) si = i;
        int bp = in_sizes[si];
        bool ok = (bp > 0) && (bp % PP == 0);
        int rem[8]; int nrem = 0;
        const float* vcand = nullptr; const float* dcand = nullptr;
        if (ok) {
            for (int i = 0; i < n_in && i < 8; ++i) {
                if (i == si) continue;
                if (!vcand && in_sizes[i] == bp * VV * 3) { vcand = (const float*)d_in[i]; continue; }
                if (!dcand && in_sizes[i] == DD * 3)      { dcand = (const float*)d_in[i]; continue; }
                rem[nrem++] = i;
            }
        }
        if (ok && vcand && nrem == 3) {
            int pci = rem[0];
            for (int r = 1; r < 3; ++r) if (in_sizes[rem[r]] > in_sizes[pci]) pci = rem[r];
            int oth[2]; int no = 0;
            for (int r = 0; r < 3; ++r) if (rem[r] != pci) oth[no++] = rem[r];
            int B = bp / PP;
            int npc = in_sizes[pci] / (3 * B);
            int nns = in_sizes[oth[0]] / (3 * B);
            int nou = in_sizes[oth[1]] / (3 * B);
            if (npc > 0 && nns > 0 && nou > 0) {
                smooth = (const float*)d_in[si];
                verts  = vcand;
                dirsin = dcand;
                pcb    = (const float*)d_in[pci];
                nsb    = (const float*)d_in[oth[0]];
                ob     = (const float*)d_in[oth[1]];
                Bv = B; BP = bp; NPCv = npc; NNSv = nns; NOUTv = nou;
            }
        }
        if (!verts) {   // fallback: dict order, reference shapes
            verts  = (const float*)d_in[0];
            smooth = (const float*)d_in[1];
            pcb    = (const float*)d_in[2];
            nsb    = (const float*)d_in[3];
            ob     = (const float*)d_in[4];
            Bv = 8; BP = 128; NPCv = 16384; NNSv = 8192; NOUTv = 8192;
        }
    }

    // ---- workspace carve ----
    double* dmean  = (double*)d_ws;              // 3*BP f64
    double* dscale = dmean + 3*(size_t)BP;       // BP f64
    float*  fdirs  = (float*)(dscale + BP);      // 2058
    float*  fmean  = fdirs + DD*3;               // 3*BP
    float*  fpe    = fmean + 3*(size_t)BP;       // BP
    float*  finvpe = fpe + BP;                   // BP
    float*  flocal = finvpe + BP;                // 96*BP
    float*  fsurf  = flocal + 96*(size_t)BP;     // 3*DD*BP

    // ---- output offsets (f32 elements) ----
    float* out = (float*)d_out;
    size_t o0 = 0;
    size_t o1 = o0 + (size_t)Bv*PP*PP;
    size_t o2 = o1 + (size_t)BP*NPCv;
    size_t o3 = o2 + (size_t)BP*DD*3;
    size_t o4 = o3 + (size_t)BP*PP*DD;
    size_t o5 = o4 + (size_t)BP*DD*3;
    size_t o6 = o5 + (size_t)BP*NNSv;

    const float* dirs = dirsin ? dirsin : fdirs;
    int nPrep = (BP + 255) / 256;
    k_setup<<<dim3(3 + nPrep), 256, 0, stream>>>(verts, smooth, dmean, fmean, flocal,
                                                 fpe, finvpe, fdirs, BP, dirsin ? 0 : 1);
    int cPC = (NPCv + 1023)/1024, cNS = (NNSv + 1023)/1024, cOU = (NOUTv + 1023)/1024;
    int cD  = cPC + cNS + cOU;
    k_work<<<dim3(BP + Bv + BP*cD), 256, 0, stream>>>(
        dirs, flocal, fmean, dmean, fpe, finvpe, dscale,
        pcb, NPCv, cPC, nsb, NNSv, cNS, ob, NOUTv, cD,
        out + o2, fsurf, out + o4, out + o0,
        out + o1, out + o5, out + o6, BP, Bv);
    k_surfdist<<<dim3(BP, (PP*DD + 255)/256), 256, 0, stream>>>(
        fsurf, dirs, flocal, dmean, fmean, fpe, finvpe, dscale, out + o3);
}